// Round 9
// baseline (180.156 us; speedup 1.0000x reference)
//
#include <hip/hip_runtime.h>
#include <math.h>

#define NN 10000
#define NE 160000

typedef __attribute__((ext_vector_type(8))) short s8v;
typedef __attribute__((ext_vector_type(4))) float f4v;
typedef unsigned short u16;

// ---- ws byte layout ----
#define OFF_P1HB 0u          // N*32 bf16      = 640000 B
#define OFF_P3HB 640000u     // N*3*32 bf16    = 1920000 B
#define OFF_WB   2560000u    // NWB bf16       = 204800 B
// CSR / store path:
#define OFF_HIST   2764800u  // 10000 int
#define OFF_CURSOR 2804800u  // 10000 int
#define OFF_START  2844800u  // 10001 int
#define OFF_RANK   2884804u  // NE int = 640000 B
#define OFF_E13    3524804u  // NE*128 u16 = 40960000 B
#define WS_NEEDED  44484804ull
// fallback (atomic) path:
#define OFF_P1N_FB 2764800u
#define OFF_P3N_FB 4044800u

// ---- wb (ushort element) offsets ----
#define OW1T1 0       // [32 c][72 kpad]  (k<64)
#define OW2T1 2304    // [96 c][40 kpad]  (k<32)
#define OII1T 6144    // [32 c][40 kpad]
#define OW1T3 7424    // [32 c][72 kpad]
#define OW2T3 9728    // [32 c][40 kpad]
#define OII3T 11008   // [32 c][40 kpad]
#define OBLG  12288   // [8 b][96 c][104 kpad]  (k<96)   = 79872
#define OBL3G 92160   // [8 b][32 c][40 kpad]   (k<32)   = 10240
#define NWB   102400

__device__ __forceinline__ short f2b(float f) {
    unsigned u = __float_as_uint(f);
    u += 0x7fffu + ((u >> 16) & 1u);
    return (short)(u >> 16);
}
__device__ __forceinline__ float b2f(u16 s) {
    return __uint_as_float(((unsigned)s) << 16);
}
__device__ __forceinline__ float tanhf_fast(float x) {
    float xc = fminf(9.f, fmaxf(-9.f, x));
    float e = __expf(2.f * xc);
    return (e - 1.f) * __builtin_amdgcn_rcpf(e + 1.f);
}

// ---------------- node prep: p1h/p3h = tanh(x@W+b) -> bf16 ----------------
__global__ __launch_bounds__(256) void node_prep(
    const float* __restrict__ p1, const float* __restrict__ p3,
    const float* __restrict__ pp1_W, const float* __restrict__ pp1_b,
    const float* __restrict__ pp3_W, const float* __restrict__ pp3_b,
    u16* __restrict__ p1hb, u16* __restrict__ p3hb)
{
    __shared__ float Ws[2][32 * 32];
    __shared__ float bsm[2][32];
    int tid = threadIdx.x;
    for (int i = tid; i < 32 * 32; i += 256) { Ws[0][i] = pp1_W[i]; Ws[1][i] = pp3_W[i]; }
    if (tid < 32) { bsm[0][tid] = pp1_b[tid]; bsm[1][tid] = pp3_b[tid]; }
    __syncthreads();
    int idx = blockIdx.x * 256 + tid;
    int n = idx >> 7;
    int r = (idx >> 5) & 3;
    int c = idx & 31;
    int sel = (r == 0) ? 0 : 1;
    const float* in = (r == 0) ? (p1 + n * 32) : (p3 + (n * 3 + (r - 1)) * 32);
    float acc = bsm[sel][c];
    #pragma unroll
    for (int k = 0; k < 32; ++k) acc += in[k] * Ws[sel][k * 32 + c];
    short v = f2b(tanhf(acc));
    if (r == 0) p1hb[n * 32 + c] = (u16)v;
    else        p3hb[(n * 3 + (r - 1)) * 32 + c] = (u16)v;
}

// ---------------- weight prep: transpose/convert to bf16 with pads --------
__global__ __launch_bounds__(256) void wprep(
    const float* __restrict__ W1, const float* __restrict__ W2,
    const float* __restrict__ W3, const float* __restrict__ ii1,
    const float* __restrict__ W13, const float* __restrict__ W23,
    const float* __restrict__ W33, const float* __restrict__ ii3,
    u16* __restrict__ wb)
{
    int i0 = blockIdx.x * 256 + threadIdx.x;
    if (i0 >= NWB) return;
    int i = i0;
    float v = 0.f;
    if (i < 2304) { int c = i / 72, k = i % 72; if (k < 64) v = W1[k * 32 + c]; }
    else if ((i -= 2304) < 3840) { int c = i / 40, k = i % 40; if (k < 32) v = W2[k * 96 + c]; }
    else if ((i -= 3840) < 1280) { int c = i / 40, k = i % 40; if (k < 32) v = ii1[k * 32 + c]; }
    else if ((i -= 1280) < 2304) { int c = i / 72, k = i % 72; if (k < 64) v = W13[k * 32 + c]; }
    else if ((i -= 2304) < 1280) { int c = i / 40, k = i % 40; if (k < 32) v = W23[k * 32 + c]; }
    else if ((i -= 1280) < 1280) { int c = i / 40, k = i % 40; if (k < 32) v = ii3[k * 32 + c]; }
    else if ((i -= 1280) < 79872) {
        int b = i / 9984, r = i % 9984, c = r / 104, k = r % 104;
        if (k < 96) v = W3[k * 768 + c * 8 + b];
    } else {
        i -= 79872;
        int b = i / 1280, r = i % 1280, c = r / 40, k = r % 40;
        if (k < 32) v = W33[k * 256 + c * 8 + b];
    }
    wb[i0] = (u16)f2b(v);
}

// ---------------- CSR build ----------------
__global__ __launch_bounds__(256) void hist_kernel(
    const int* __restrict__ idx_j, int* __restrict__ hist)
{
    int e = blockIdx.x * 256 + threadIdx.x;
    if (e < NE) atomicAdd(&hist[idx_j[e]], 1);
}

__global__ __launch_bounds__(256) void scan_kernel(
    const int* __restrict__ hist, int* __restrict__ start, int* __restrict__ cursor)
{
    __shared__ int part[256];
    int t = threadIdx.x;
    int base = t * 40;
    int s = 0;
    for (int i = 0; i < 40; ++i) { int idx = base + i; if (idx < NN) s += hist[idx]; }
    part[t] = s;
    __syncthreads();
    for (int off = 1; off < 256; off <<= 1) {
        int v = (t >= off) ? part[t - off] : 0;
        __syncthreads();
        part[t] += v;
        __syncthreads();
    }
    int run = part[t] - s;
    for (int i = 0; i < 40; ++i) {
        int idx = base + i;
        if (idx < NN) {
            int h = hist[idx];
            start[idx] = run; cursor[idx] = run; run += h;
        }
    }
    if (t == 255) start[NN] = part[255];
}

__global__ __launch_bounds__(256) void rank_kernel(
    const int* __restrict__ idx_j, int* __restrict__ cursor, int* __restrict__ rank)
{
    int e = blockIdx.x * 256 + threadIdx.x;
    if (e < NE) rank[e] = atomicAdd(&cursor[idx_j[e]], 1);
}

// ------- fused edge kernel: 64 edges per 1-wave block (4 M-tiles) ---------
// MODE 0: store per-edge results to e13[rank[e]*128] (CSR-sorted rows).
// MODE 1: atomic fallback.
// launch_bounds(64,2): 256-VGPR cap; (64,4) spilled 1.3 GB (round 6).
template <int MODE>
__global__ __launch_bounds__(64, 2) void edge_kernel(
    const u16* __restrict__ p1hb, const u16* __restrict__ p3hb,
    const float* __restrict__ r3, const float* __restrict__ basis,
    const int* __restrict__ idx_i, const int* __restrict__ idx_j,
    const int* __restrict__ rank, const u16* __restrict__ wb,
    const float* __restrict__ b1, const float* __restrict__ b2,
    const float* __restrict__ ii1b,
    const float* __restrict__ b13, const float* __restrict__ b23,
    const float* __restrict__ ii3b,
    u16* __restrict__ e13, float* __restrict__ p1n, float* __restrict__ p3n)
{
    // 8.25 KB LDS, single wave per block
    __shared__ int4 smem4[528];
    char* sw = (char*)smem4;
    int*   sIdxI = (int*)(sw + 0);       // [64]
    int*   sIdxJ = (int*)(sw + 256);     // [64]
    float* sBasT = (float*)(sw + 512);   // [8][64] transposed basis
    float* sR3   = (float*)(sw + 2560);  // [3][64]
    u16*   sT1   = (u16*)(sw + 3584);    // [16][104] h2 transpose buffer
    u16*   sT2   = (u16*)(sw + 6912);    // [16][40]  small transpose buffer
    int*   sRank = (int*)(sw + 8192);    // [64]

    const int l   = threadIdx.x & 63;
    const int r16 = l & 15;
    const int kg  = l >> 4;
    const int ebase = blockIdx.x * 64;

    // ---- staging ----
    sIdxI[l] = idx_i[ebase + l];
    sIdxJ[l] = idx_j[ebase + l];
    if (MODE == 0) sRank[l] = rank[ebase + l];
    {
        const float4* bp = (const float4*)(basis + (size_t)(ebase + l) * 8);
        float4 q0 = bp[0], q1 = bp[1];
        sBasT[0 * 64 + l] = q0.x; sBasT[1 * 64 + l] = q0.y;
        sBasT[2 * 64 + l] = q0.z; sBasT[3 * 64 + l] = q0.w;
        sBasT[4 * 64 + l] = q1.x; sBasT[5 * 64 + l] = q1.y;
        sBasT[6 * 64 + l] = q1.z; sBasT[7 * 64 + l] = q1.w;
        sR3[l]       = r3[(size_t)(ebase + l) * 3 + 0];
        sR3[64 + l]  = r3[(size_t)(ebase + l) * 3 + 1];
        sR3[128 + l] = r3[(size_t)(ebase + l) * 3 + 2];
    }

    // bias registers (per-lane channel slices)
    const float vb1[2]  = { b1[r16],   b1[16 + r16] };
    float vb2[6];
    #pragma unroll
    for (int nt = 0; nt < 6; ++nt) vb2[nt] = b2[16 * nt + r16];
    const float vii1[2] = { ii1b[r16], ii1b[16 + r16] };
    const float vb13[2] = { b13[r16],  b13[16 + r16] };
    const float vb23[2] = { b23[r16],  b23[16 + r16] };
    const float vii3[2] = { ii3b[r16], ii3b[16 + r16] };

    const f4v zf = {0.f, 0.f, 0.f, 0.f};

    // ---- Phase A: per M-tile pi1 front (h1 -> h2 -> af regs) ----
    s8v af[4][3];
    f4v accT[4][6];
    #pragma unroll
    for (int m = 0; m < 4; ++m)
        #pragma unroll
        for (int nt = 0; nt < 6; ++nt) accT[m][nt] = zf;

    const u16* gW1 = wb + OW1T1;
    const u16* gW2 = wb + OW2T1;
    #pragma unroll
    for (int m = 0; m < 4; ++m) {
        int rowA = m * 16 + r16;
        int ni = sIdxI[rowA], nj = sIdxJ[rowA];
        s8v av0 = *(const s8v*)(p1hb + (size_t)ni * 32 + kg * 8);
        s8v av1 = *(const s8v*)(p1hb + (size_t)nj * 32 + kg * 8);
        #pragma unroll
        for (int nt = 0; nt < 2; ++nt) {
            s8v bv0 = *(const s8v*)(gW1 + (16 * nt + r16) * 72 + 8 * kg);
            s8v bv1 = *(const s8v*)(gW1 + (16 * nt + r16) * 72 + 32 + 8 * kg);
            f4v a = __builtin_amdgcn_mfma_f32_16x16x32_bf16(av0, bv0, zf, 0, 0, 0);
            a = __builtin_amdgcn_mfma_f32_16x16x32_bf16(av1, bv1, a, 0, 0, 0);
            #pragma unroll
            for (int rr = 0; rr < 4; ++rr)
                sT2[(4 * kg + rr) * 40 + 16 * nt + r16] = (u16)f2b(a[rr] + vb1[nt]);
        }
        s8v av2 = *(const s8v*)(sT2 + r16 * 40 + 8 * kg);
        #pragma unroll
        for (int nt = 0; nt < 6; ++nt) {
            s8v bv = *(const s8v*)(gW2 + (16 * nt + r16) * 40 + 8 * kg);
            f4v acc = __builtin_amdgcn_mfma_f32_16x16x32_bf16(av2, bv, zf, 0, 0, 0);
            #pragma unroll
            for (int rr = 0; rr < 4; ++rr)
                sT1[(4 * kg + rr) * 104 + 16 * nt + r16] = (u16)f2b(acc[rr] + vb2[nt]);
        }
        af[m][0] = *(const s8v*)(sT1 + r16 * 104 + 8 * kg);
        af[m][1] = *(const s8v*)(sT1 + r16 * 104 + 32 + 8 * kg);
        af[m][2] = *(const s8v*)(sT1 + r16 * 104 + 64 + 8 * kg);
    }

    // ---- Phase B: pi1-W3 b-form, B reused across 4 M-tiles ----
    {
        const u16* gBl = wb + OBLG;
        #pragma unroll 2
        for (int b = 0; b < 8; ++b) {
            float tb[4][4];
            #pragma unroll
            for (int m = 0; m < 4; ++m)
                #pragma unroll
                for (int rr = 0; rr < 4; ++rr)
                    tb[m][rr] = sBasT[b * 64 + m * 16 + 4 * kg + rr];
            #pragma unroll
            for (int nt = 0; nt < 6; ++nt) {
                const u16* bp = gBl + (size_t)b * 9984 + (16 * nt + r16) * 104 + 8 * kg;
                s8v bv0 = *(const s8v*)(bp);
                s8v bv1 = *(const s8v*)(bp + 32);
                s8v bv2 = *(const s8v*)(bp + 64);
                #pragma unroll
                for (int m = 0; m < 4; ++m) {
                    f4v D = __builtin_amdgcn_mfma_f32_16x16x32_bf16(af[m][0], bv0, zf, 0, 0, 0);
                    D = __builtin_amdgcn_mfma_f32_16x16x32_bf16(af[m][1], bv1, D, 0, 0, 0);
                    D = __builtin_amdgcn_mfma_f32_16x16x32_bf16(af[m][2], bv2, D, 0, 0, 0);
                    #pragma unroll
                    for (int rr = 0; rr < 4; ++rr)
                        accT[m][nt][rr] += tb[m][rr] * D[rr];
                }
            }
        }
    }

    // ---- Phase C: ii1 = tanh(i1_1 @ ii1_W + b) -> store/atomic ----
    {
        const u16* gII = wb + OII1T;
        #pragma unroll
        for (int m = 0; m < 4; ++m) {
            #pragma unroll
            for (int nt = 0; nt < 2; ++nt)
                #pragma unroll
                for (int rr = 0; rr < 4; ++rr)
                    sT2[(4 * kg + rr) * 40 + 16 * nt + r16] = (u16)f2b(accT[m][nt][rr]);
            s8v av = *(const s8v*)(sT2 + r16 * 40 + 8 * kg);
            #pragma unroll
            for (int nt = 0; nt < 2; ++nt) {
                s8v bv = *(const s8v*)(gII + (16 * nt + r16) * 40 + 8 * kg);
                f4v ia = __builtin_amdgcn_mfma_f32_16x16x32_bf16(av, bv, zf, 0, 0, 0);
                #pragma unroll
                for (int rr = 0; rr < 4; ++rr) {
                    int rowD = m * 16 + 4 * kg + rr;
                    float v = tanhf_fast(ia[rr] + vii1[nt]);
                    if (MODE == 0)
                        e13[(size_t)sRank[rowD] * 128 + 16 * nt + r16] = (u16)f2b(v);
                    else
                        atomicAdd(&p1n[(size_t)sIdxJ[rowD] * 32 + 16 * nt + r16], v);
                }
            }
        }
    }

    // ---- Phase D: pi3 branch per Cartesian d ----
    const u16* gW13 = wb + OW1T3;
    const u16* gW23 = wb + OW2T3;
    const u16* gII3 = wb + OII3T;
    const u16* gBl3 = wb + OBL3G;
    for (int d = 0; d < 3; ++d) {
        s8v avG2[4];
        #pragma unroll
        for (int m = 0; m < 4; ++m) {
            int rowA = m * 16 + r16;
            int ni = sIdxI[rowA], nj = sIdxJ[rowA];
            s8v av0 = *(const s8v*)(p3hb + ((size_t)ni * 3 + d) * 32 + kg * 8);
            s8v av1 = *(const s8v*)(p3hb + ((size_t)nj * 3 + d) * 32 + kg * 8);
            #pragma unroll
            for (int nt = 0; nt < 2; ++nt) {
                s8v bv0 = *(const s8v*)(gW13 + (16 * nt + r16) * 72 + 8 * kg);
                s8v bv1 = *(const s8v*)(gW13 + (16 * nt + r16) * 72 + 32 + 8 * kg);
                f4v g = __builtin_amdgcn_mfma_f32_16x16x32_bf16(av0, bv0, zf, 0, 0, 0);
                g = __builtin_amdgcn_mfma_f32_16x16x32_bf16(av1, bv1, g, 0, 0, 0);
                #pragma unroll
                for (int rr = 0; rr < 4; ++rr)
                    sT2[(4 * kg + rr) * 40 + 16 * nt + r16] = (u16)f2b(g[rr] + vb13[nt]);
            }
            s8v avg = *(const s8v*)(sT2 + r16 * 40 + 8 * kg);
            #pragma unroll
            for (int nt = 0; nt < 2; ++nt) {
                s8v bv = *(const s8v*)(gW23 + (16 * nt + r16) * 40 + 8 * kg);
                f4v g2 = __builtin_amdgcn_mfma_f32_16x16x32_bf16(avg, bv, zf, 0, 0, 0);
                #pragma unroll
                for (int rr = 0; rr < 4; ++rr)
                    sT2[(4 * kg + rr) * 40 + 16 * nt + r16] = (u16)f2b(g2[rr] + vb23[nt]);
            }
            avG2[m] = *(const s8v*)(sT2 + r16 * 40 + 8 * kg);
        }
        // W33 b-form with 4-M reuse
        f4v accP[4][2];
        #pragma unroll
        for (int m = 0; m < 4; ++m) { accP[m][0] = zf; accP[m][1] = zf; }
        #pragma unroll 2
        for (int b = 0; b < 8; ++b) {
            float tb[4][4];
            #pragma unroll
            for (int m = 0; m < 4; ++m)
                #pragma unroll
                for (int rr = 0; rr < 4; ++rr)
                    tb[m][rr] = sBasT[b * 64 + m * 16 + 4 * kg + rr];
            #pragma unroll
            for (int nt = 0; nt < 2; ++nt) {
                s8v bv = *(const s8v*)(gBl3 + (size_t)b * 1280 + (16 * nt + r16) * 40 + 8 * kg);
                #pragma unroll
                for (int m = 0; m < 4; ++m) {
                    f4v D = __builtin_amdgcn_mfma_f32_16x16x32_bf16(avG2[m], bv, zf, 0, 0, 0);
                    #pragma unroll
                    for (int rr = 0; rr < 4; ++rr)
                        accP[m][nt][rr] += tb[m][rr] * D[rr];
                }
            }
        }
        // ii3 + combine + store/atomic
        #pragma unroll
        for (int m = 0; m < 4; ++m) {
            #pragma unroll
            for (int nt = 0; nt < 2; ++nt)
                #pragma unroll
                for (int rr = 0; rr < 4; ++rr)
                    sT2[(4 * kg + rr) * 40 + 16 * nt + r16] = (u16)f2b(accP[m][nt][rr]);
            s8v av = *(const s8v*)(sT2 + r16 * 40 + 8 * kg);
            #pragma unroll
            for (int nt = 0; nt < 2; ++nt) {
                s8v bv = *(const s8v*)(gII3 + (16 * nt + r16) * 40 + 8 * kg);
                f4v ja = __builtin_amdgcn_mfma_f32_16x16x32_bf16(av, bv, zf, 0, 0, 0);
                #pragma unroll
                for (int rr = 0; rr < 4; ++rr) {
                    int rowD = m * 16 + 4 * kg + rr;
                    float i3a = tanhf_fast(ja[rr] + vii3[nt]);
                    float val = i3a * accT[m][2 + nt][rr] + sR3[d * 64 + rowD] * accT[m][4 + nt][rr];
                    if (MODE == 0)
                        e13[(size_t)sRank[rowD] * 128 + 32 + 32 * d + 16 * nt + r16] = (u16)f2b(val);
                    else
                        atomicAdd(&p3n[((size_t)sIdxJ[rowD] * 3 + d) * 32 + 16 * nt + r16], val);
                }
            }
        }
    }
}

// ------- gather + finalize: 1 wave per node, contiguous CSR rows ----------
__global__ __launch_bounds__(256) void gather2(
    const u16* __restrict__ e13, const int* __restrict__ start,
    float* __restrict__ out)
{
    int node = blockIdx.x * 4 + (threadIdx.x >> 6);
    int l = threadIdx.x & 63;
    int st = start[node], en = start[node + 1];
    int deg = en - st;
    float a0 = 0.f, a1 = 0.f;
    const u16* base = e13 + (size_t)st * 128 + 2 * l;
    int k = 0;
    for (; k + 4 <= deg; k += 4) {
        unsigned v0 = *(const unsigned*)(base + (size_t)(k + 0) * 128);
        unsigned v1 = *(const unsigned*)(base + (size_t)(k + 1) * 128);
        unsigned v2 = *(const unsigned*)(base + (size_t)(k + 2) * 128);
        unsigned v3 = *(const unsigned*)(base + (size_t)(k + 3) * 128);
        a0 += b2f((u16)(v0 & 0xffffu)) + b2f((u16)(v1 & 0xffffu))
            + b2f((u16)(v2 & 0xffffu)) + b2f((u16)(v3 & 0xffffu));
        a1 += b2f((u16)(v0 >> 16)) + b2f((u16)(v1 >> 16))
            + b2f((u16)(v2 >> 16)) + b2f((u16)(v3 >> 16));
    }
    for (; k < deg; ++k) {
        unsigned v = *(const unsigned*)(base + (size_t)k * 128);
        a0 += b2f((u16)(v & 0xffffu));
        a1 += b2f((u16)(v >> 16));
    }
    int q = l & 15, g = l >> 4;
    float s00 = __shfl(a0, q),      s10 = __shfl(a1, q);
    float s01 = __shfl(a0, 16 + q), s11 = __shfl(a1, 16 + q);
    float s02 = __shfl(a0, 32 + q), s12 = __shfl(a1, 32 + q);
    float s03 = __shfl(a0, 48 + q), s13 = __shfl(a1, 48 + q);
    float p1o0 = s00 + s01 * s01 + s02 * s02 + s03 * s03;
    float p1o1 = s10 + s11 * s11 + s12 * s12 + s13 * s13;
    if (g == 0) {
        *(float2*)(out + (size_t)node * 32 + 2 * q) = make_float2(p1o0, p1o1);
    } else {
        float2 v = make_float2(a0 * p1o0, a1 * p1o1);
        *(float2*)(out + (size_t)NN * 32 + ((size_t)node * 3 + (g - 1)) * 32 + 2 * q) = v;
    }
}

// ---------------- finalize (fallback path only) ---------------------------
__global__ __launch_bounds__(256) void finalize_kernel(
    const float* __restrict__ p1n, const float* __restrict__ p3n,
    float* __restrict__ out)
{
    int t = blockIdx.x * 256 + threadIdx.x;
    int n = t >> 5, c = t & 31;
    float a0 = p3n[(n * 3 + 0) * 32 + c];
    float a1 = p3n[(n * 3 + 1) * 32 + c];
    float a2 = p3n[(n * 3 + 2) * 32 + c];
    float p1o = p1n[t] + a0 * a0 + a1 * a1 + a2 * a2;
    out[t] = p1o;
    float* o3 = out + NN * 32;
    o3[(n * 3 + 0) * 32 + c] = a0 * p1o;
    o3[(n * 3 + 1) * 32 + c] = a1 * p1o;
    o3[(n * 3 + 2) * 32 + c] = a2 * p1o;
}

extern "C" void kernel_launch(void* const* d_in, const int* in_sizes, int n_in,
                              void* d_out, int out_size, void* d_ws, size_t ws_size,
                              hipStream_t stream) {
    const float* p1     = (const float*)d_in[0];
    const float* p3     = (const float*)d_in[1];
    const float* r3     = (const float*)d_in[2];
    const float* basis  = (const float*)d_in[3];
    const int*   idx_i  = (const int*)d_in[4];
    const int*   idx_j  = (const int*)d_in[5];
    const float* pp1_W  = (const float*)d_in[6];
    const float* pp1_b  = (const float*)d_in[7];
    const float* pi1_W1 = (const float*)d_in[8];
    const float* pi1_b1 = (const float*)d_in[9];
    const float* pi1_W2 = (const float*)d_in[10];
    const float* pi1_b2 = (const float*)d_in[11];
    const float* pi1_W3 = (const float*)d_in[12];
    const float* ii1_W  = (const float*)d_in[13];
    const float* ii1_b  = (const float*)d_in[14];
    const float* pp3_W  = (const float*)d_in[15];
    const float* pp3_b  = (const float*)d_in[16];
    const float* pi3_W1 = (const float*)d_in[17];
    const float* pi3_b1 = (const float*)d_in[18];
    const float* pi3_W2 = (const float*)d_in[19];
    const float* pi3_b2 = (const float*)d_in[20];
    const float* pi3_W3 = (const float*)d_in[21];
    const float* ii3_W  = (const float*)d_in[22];
    const float* ii3_b  = (const float*)d_in[23];

    char* ws = (char*)d_ws;
    u16*   p1hb = (u16*)(ws + OFF_P1HB);
    u16*   p3hb = (u16*)(ws + OFF_P3HB);
    u16*   wb   = (u16*)(ws + OFF_WB);

    node_prep<<<dim3(5000), dim3(256), 0, stream>>>(p1, p3, pp1_W, pp1_b, pp3_W, pp3_b, p1hb, p3hb);
    wprep<<<dim3((NWB + 255) / 256), dim3(256), 0, stream>>>(
        pi1_W1, pi1_W2, pi1_W3, ii1_W, pi3_W1, pi3_W2, pi3_W3, ii3_W, wb);

    if (ws_size >= WS_NEEDED) {
        int* hist   = (int*)(ws + OFF_HIST);
        int* cursor = (int*)(ws + OFF_CURSOR);
        int* startA = (int*)(ws + OFF_START);
        int* rank   = (int*)(ws + OFF_RANK);
        u16* e13    = (u16*)(ws + OFF_E13);

        hipMemsetAsync(hist, 0, NN * sizeof(int), stream);
        hist_kernel<<<dim3((NE + 255) / 256), dim3(256), 0, stream>>>(idx_j, hist);
        scan_kernel<<<dim3(1), dim3(256), 0, stream>>>(hist, startA, cursor);
        rank_kernel<<<dim3((NE + 255) / 256), dim3(256), 0, stream>>>(idx_j, cursor, rank);

        edge_kernel<0><<<dim3(NE / 64), dim3(64), 0, stream>>>(
            p1hb, p3hb, r3, basis, idx_i, idx_j, rank, wb,
            pi1_b1, pi1_b2, ii1_b, pi3_b1, pi3_b2, ii3_b,
            e13, nullptr, nullptr);

        gather2<<<dim3(2500), dim3(256), 0, stream>>>(e13, startA, (float*)d_out);
    } else {
        float* p1n = (float*)(ws + OFF_P1N_FB);
        float* p3n = (float*)(ws + OFF_P3N_FB);
        hipMemsetAsync(p1n, 0, 5120000, stream);
        edge_kernel<1><<<dim3(NE / 64), dim3(64), 0, stream>>>(
            p1hb, p3hb, r3, basis, idx_i, idx_j, nullptr, wb,
            pi1_b1, pi1_b2, ii1_b, pi3_b1, pi3_b2, ii3_b,
            nullptr, p1n, p3n);
        finalize_kernel<<<dim3(1250), dim3(256), 0, stream>>>(p1n, p3n, (float*)d_out);
    }
}

// Round 10
// 134.673 us; speedup vs baseline: 1.3377x; 1.3377x over previous
//
#include <hip/hip_runtime.h>
#include <math.h>

#define NN 10000
#define NE 160000

typedef __attribute__((ext_vector_type(8))) short s8v;
typedef __attribute__((ext_vector_type(4))) float f4v;
typedef unsigned short u16;

// ---- ws byte layout ----
#define OFF_P1HB 0u          // N*32 bf16      = 640000 B
#define OFF_P3HB 640000u     // N*3*32 bf16    = 1920000 B
#define OFF_WB   2560000u    // NWB bf16       = 204800 B
#define OFF_P1N  2764800u    // N*32 f32       = 1280000 B
#define OFF_P3N  4044800u    // N*3*32 f32     = 3840000 B

// ---- wb (ushort element) offsets ----
#define OW1T1 0       // [32 c][72 kpad]  (k<64)
#define OW2T1 2304    // [96 c][40 kpad]  (k<32)
#define OII1T 6144    // [32 c][40 kpad]
#define OW1T3 7424    // [32 c][72 kpad]
#define OW2T3 9728    // [32 c][40 kpad]
#define OII3T 11008   // [32 c][40 kpad]
#define OBLG  12288   // [8 b][96 c][104 kpad]  (k<96)   = 79872
#define OBL3G 92160   // [8 b][32 c][40 kpad]   (k<32)   = 10240
#define NWB   102400

__device__ __forceinline__ short f2b(float f) {
    unsigned u = __float_as_uint(f);
    u += 0x7fffu + ((u >> 16) & 1u);
    return (short)(u >> 16);
}
__device__ __forceinline__ float tanhf_fast(float x) {
    float xc = fminf(9.f, fmaxf(-9.f, x));
    float e = __expf(2.f * xc);
    return (e - 1.f) * __builtin_amdgcn_rcpf(e + 1.f);
}

// ---------------- node prep: p1h/p3h = tanh(x@W+b) -> bf16 ----------------
__global__ __launch_bounds__(256) void node_prep(
    const float* __restrict__ p1, const float* __restrict__ p3,
    const float* __restrict__ pp1_W, const float* __restrict__ pp1_b,
    const float* __restrict__ pp3_W, const float* __restrict__ pp3_b,
    u16* __restrict__ p1hb, u16* __restrict__ p3hb)
{
    __shared__ float Ws[2][32 * 32];
    __shared__ float bsm[2][32];
    int tid = threadIdx.x;
    for (int i = tid; i < 32 * 32; i += 256) { Ws[0][i] = pp1_W[i]; Ws[1][i] = pp3_W[i]; }
    if (tid < 32) { bsm[0][tid] = pp1_b[tid]; bsm[1][tid] = pp3_b[tid]; }
    __syncthreads();
    int idx = blockIdx.x * 256 + tid;
    int n = idx >> 7;
    int r = (idx >> 5) & 3;
    int c = idx & 31;
    int sel = (r == 0) ? 0 : 1;
    const float* in = (r == 0) ? (p1 + n * 32) : (p3 + (n * 3 + (r - 1)) * 32);
    float acc = bsm[sel][c];
    #pragma unroll
    for (int k = 0; k < 32; ++k) acc += in[k] * Ws[sel][k * 32 + c];
    short v = f2b(tanhf(acc));
    if (r == 0) p1hb[n * 32 + c] = (u16)v;
    else        p3hb[(n * 3 + (r - 1)) * 32 + c] = (u16)v;
}

// ---------------- weight prep: transpose/convert to bf16 with pads --------
__global__ __launch_bounds__(256) void wprep(
    const float* __restrict__ W1, const float* __restrict__ W2,
    const float* __restrict__ W3, const float* __restrict__ ii1,
    const float* __restrict__ W13, const float* __restrict__ W23,
    const float* __restrict__ W33, const float* __restrict__ ii3,
    u16* __restrict__ wb)
{
    int i0 = blockIdx.x * 256 + threadIdx.x;
    if (i0 >= NWB) return;
    int i = i0;
    float v = 0.f;
    if (i < 2304) { int c = i / 72, k = i % 72; if (k < 64) v = W1[k * 32 + c]; }
    else if ((i -= 2304) < 3840) { int c = i / 40, k = i % 40; if (k < 32) v = W2[k * 96 + c]; }
    else if ((i -= 3840) < 1280) { int c = i / 40, k = i % 40; if (k < 32) v = ii1[k * 32 + c]; }
    else if ((i -= 1280) < 2304) { int c = i / 72, k = i % 72; if (k < 64) v = W13[k * 32 + c]; }
    else if ((i -= 2304) < 1280) { int c = i / 40, k = i % 40; if (k < 32) v = W23[k * 32 + c]; }
    else if ((i -= 1280) < 1280) { int c = i / 40, k = i % 40; if (k < 32) v = ii3[k * 32 + c]; }
    else if ((i -= 1280) < 79872) {
        int b = i / 9984, r = i % 9984, c = r / 104, k = r % 104;
        if (k < 96) v = W3[k * 768 + c * 8 + b];
    } else {
        i -= 79872;
        int b = i / 1280, r = i % 1280, c = r / 40, k = r % 40;
        if (k < 32) v = W33[k * 256 + c * 8 + b];
    }
    wb[i0] = (u16)f2b(v);
}

// ------- fused edge kernel: 32 edges per 1-wave block (2 M-tiles) ---------
// launch_bounds(64,3): VGPR cap ~170 (pool 512/SIMD, m69 halving points);
// per-wave need ~150 at M=2 (accT 48 + af 24 + accP 16 + temps). 3 resident
// waves/SIMD vs round-8's 2.44, each wave half as long -> stalls overlap.
__global__ __launch_bounds__(64, 3) void edge_kernel(
    const u16* __restrict__ p1hb, const u16* __restrict__ p3hb,
    const float* __restrict__ r3, const float* __restrict__ basis,
    const int* __restrict__ idx_i, const int* __restrict__ idx_j,
    const u16* __restrict__ wb,
    const float* __restrict__ b1, const float* __restrict__ b2,
    const float* __restrict__ ii1b,
    const float* __restrict__ b13, const float* __restrict__ b23,
    const float* __restrict__ ii3b,
    float* __restrict__ p1n, float* __restrict__ p3n)
{
    // 6.3 KB LDS, single wave per block
    __shared__ int4 smem4[400];
    char* sw = (char*)smem4;
    int*   sIdxI = (int*)(sw + 0);       // [32]
    int*   sIdxJ = (int*)(sw + 128);     // [32]
    float* sBasT = (float*)(sw + 256);   // [8][32] transposed basis
    float* sR3   = (float*)(sw + 1280);  // [3][32]
    u16*   sT1   = (u16*)(sw + 1664);    // [16][104] h2 transpose buffer
    u16*   sT2   = (u16*)(sw + 4992);    // [16][40]  small transpose buffer

    const int l   = threadIdx.x & 63;
    const int r16 = l & 15;
    const int kg  = l >> 4;
    const int ebase = blockIdx.x * 32;

    // ---- staging (single wave: in-order LDS, no barriers) ----
    if (l < 32) sIdxI[l] = idx_i[ebase + l];
    else        sIdxJ[l - 32] = idx_j[ebase + l - 32];
    {
        int e = l & 31, hf = l >> 5;
        const float4* bp = (const float4*)(basis + (size_t)(ebase + e) * 8);
        float4 q = bp[hf];
        sBasT[(4 * hf + 0) * 32 + e] = q.x;
        sBasT[(4 * hf + 1) * 32 + e] = q.y;
        sBasT[(4 * hf + 2) * 32 + e] = q.z;
        sBasT[(4 * hf + 3) * 32 + e] = q.w;
        if (hf == 0) {
            sR3[e]      = r3[(size_t)(ebase + e) * 3 + 0];
            sR3[32 + e] = r3[(size_t)(ebase + e) * 3 + 1];
            sR3[64 + e] = r3[(size_t)(ebase + e) * 3 + 2];
        }
    }

    // bias registers (per-lane channel slices)
    const float vb1[2]  = { b1[r16],   b1[16 + r16] };
    float vb2[6];
    #pragma unroll
    for (int nt = 0; nt < 6; ++nt) vb2[nt] = b2[16 * nt + r16];
    const float vii1[2] = { ii1b[r16], ii1b[16 + r16] };
    const float vb13[2] = { b13[r16],  b13[16 + r16] };
    const float vb23[2] = { b23[r16],  b23[16 + r16] };
    const float vii3[2] = { ii3b[r16], ii3b[16 + r16] };

    const f4v zf = {0.f, 0.f, 0.f, 0.f};

    // ---- Phase A: per M-tile pi1 front (h1 -> h2 -> af regs) ----
    s8v af[2][3];
    f4v accT[2][6];
    #pragma unroll
    for (int m = 0; m < 2; ++m)
        #pragma unroll
        for (int nt = 0; nt < 6; ++nt) accT[m][nt] = zf;

    const u16* gW1 = wb + OW1T1;
    const u16* gW2 = wb + OW2T1;
    #pragma unroll
    for (int m = 0; m < 2; ++m) {
        int rowA = m * 16 + r16;
        int ni = sIdxI[rowA], nj = sIdxJ[rowA];
        s8v av0 = *(const s8v*)(p1hb + (size_t)ni * 32 + kg * 8);
        s8v av1 = *(const s8v*)(p1hb + (size_t)nj * 32 + kg * 8);
        #pragma unroll
        for (int nt = 0; nt < 2; ++nt) {
            s8v bv0 = *(const s8v*)(gW1 + (16 * nt + r16) * 72 + 8 * kg);
            s8v bv1 = *(const s8v*)(gW1 + (16 * nt + r16) * 72 + 32 + 8 * kg);
            f4v a = __builtin_amdgcn_mfma_f32_16x16x32_bf16(av0, bv0, zf, 0, 0, 0);
            a = __builtin_amdgcn_mfma_f32_16x16x32_bf16(av1, bv1, a, 0, 0, 0);
            #pragma unroll
            for (int rr = 0; rr < 4; ++rr)
                sT2[(4 * kg + rr) * 40 + 16 * nt + r16] = (u16)f2b(a[rr] + vb1[nt]);
        }
        s8v av2 = *(const s8v*)(sT2 + r16 * 40 + 8 * kg);
        #pragma unroll
        for (int nt = 0; nt < 6; ++nt) {
            s8v bv = *(const s8v*)(gW2 + (16 * nt + r16) * 40 + 8 * kg);
            f4v acc = __builtin_amdgcn_mfma_f32_16x16x32_bf16(av2, bv, zf, 0, 0, 0);
            #pragma unroll
            for (int rr = 0; rr < 4; ++rr)
                sT1[(4 * kg + rr) * 104 + 16 * nt + r16] = (u16)f2b(acc[rr] + vb2[nt]);
        }
        af[m][0] = *(const s8v*)(sT1 + r16 * 104 + 8 * kg);
        af[m][1] = *(const s8v*)(sT1 + r16 * 104 + 32 + 8 * kg);
        af[m][2] = *(const s8v*)(sT1 + r16 * 104 + 64 + 8 * kg);
    }

    // ---- Phase B: pi1-W3 b-form, B reused across 2 M-tiles ----
    {
        const u16* gBl = wb + OBLG;
        #pragma unroll 2
        for (int b = 0; b < 8; ++b) {
            float tb[2][4];
            #pragma unroll
            for (int m = 0; m < 2; ++m)
                #pragma unroll
                for (int rr = 0; rr < 4; ++rr)
                    tb[m][rr] = sBasT[b * 32 + m * 16 + 4 * kg + rr];
            #pragma unroll
            for (int nt = 0; nt < 6; ++nt) {
                const u16* bp = gBl + (size_t)b * 9984 + (16 * nt + r16) * 104 + 8 * kg;
                s8v bv0 = *(const s8v*)(bp);
                s8v bv1 = *(const s8v*)(bp + 32);
                s8v bv2 = *(const s8v*)(bp + 64);
                #pragma unroll
                for (int m = 0; m < 2; ++m) {
                    f4v D = __builtin_amdgcn_mfma_f32_16x16x32_bf16(af[m][0], bv0, zf, 0, 0, 0);
                    D = __builtin_amdgcn_mfma_f32_16x16x32_bf16(af[m][1], bv1, D, 0, 0, 0);
                    D = __builtin_amdgcn_mfma_f32_16x16x32_bf16(af[m][2], bv2, D, 0, 0, 0);
                    #pragma unroll
                    for (int rr = 0; rr < 4; ++rr)
                        accT[m][nt][rr] += tb[m][rr] * D[rr];
                }
            }
        }
    }

    // ---- Phase C: ii1 = tanh(i1_1 @ ii1_W + b) -> atomic p1n[idx_j] ----
    {
        const u16* gII = wb + OII1T;
        #pragma unroll
        for (int m = 0; m < 2; ++m) {
            #pragma unroll
            for (int nt = 0; nt < 2; ++nt)
                #pragma unroll
                for (int rr = 0; rr < 4; ++rr)
                    sT2[(4 * kg + rr) * 40 + 16 * nt + r16] = (u16)f2b(accT[m][nt][rr]);
            s8v av = *(const s8v*)(sT2 + r16 * 40 + 8 * kg);
            #pragma unroll
            for (int nt = 0; nt < 2; ++nt) {
                s8v bv = *(const s8v*)(gII + (16 * nt + r16) * 40 + 8 * kg);
                f4v ia = __builtin_amdgcn_mfma_f32_16x16x32_bf16(av, bv, zf, 0, 0, 0);
                #pragma unroll
                for (int rr = 0; rr < 4; ++rr) {
                    int rowD = m * 16 + 4 * kg + rr;
                    atomicAdd(&p1n[(size_t)sIdxJ[rowD] * 32 + 16 * nt + r16],
                              tanhf_fast(ia[rr] + vii1[nt]));
                }
            }
        }
    }

    // ---- Phase D: pi3 branch per Cartesian d ----
    const u16* gW13 = wb + OW1T3;
    const u16* gW23 = wb + OW2T3;
    const u16* gII3 = wb + OII3T;
    const u16* gBl3 = wb + OBL3G;
    for (int d = 0; d < 3; ++d) {
        s8v avG2[2];
        #pragma unroll
        for (int m = 0; m < 2; ++m) {
            int rowA = m * 16 + r16;
            int ni = sIdxI[rowA], nj = sIdxJ[rowA];
            s8v av0 = *(const s8v*)(p3hb + ((size_t)ni * 3 + d) * 32 + kg * 8);
            s8v av1 = *(const s8v*)(p3hb + ((size_t)nj * 3 + d) * 32 + kg * 8);
            #pragma unroll
            for (int nt = 0; nt < 2; ++nt) {
                s8v bv0 = *(const s8v*)(gW13 + (16 * nt + r16) * 72 + 8 * kg);
                s8v bv1 = *(const s8v*)(gW13 + (16 * nt + r16) * 72 + 32 + 8 * kg);
                f4v g = __builtin_amdgcn_mfma_f32_16x16x32_bf16(av0, bv0, zf, 0, 0, 0);
                g = __builtin_amdgcn_mfma_f32_16x16x32_bf16(av1, bv1, g, 0, 0, 0);
                #pragma unroll
                for (int rr = 0; rr < 4; ++rr)
                    sT2[(4 * kg + rr) * 40 + 16 * nt + r16] = (u16)f2b(g[rr] + vb13[nt]);
            }
            s8v avg = *(const s8v*)(sT2 + r16 * 40 + 8 * kg);
            #pragma unroll
            for (int nt = 0; nt < 2; ++nt) {
                s8v bv = *(const s8v*)(gW23 + (16 * nt + r16) * 40 + 8 * kg);
                f4v g2 = __builtin_amdgcn_mfma_f32_16x16x32_bf16(avg, bv, zf, 0, 0, 0);
                #pragma unroll
                for (int rr = 0; rr < 4; ++rr)
                    sT2[(4 * kg + rr) * 40 + 16 * nt + r16] = (u16)f2b(g2[rr] + vb23[nt]);
            }
            avG2[m] = *(const s8v*)(sT2 + r16 * 40 + 8 * kg);
        }
        // W33 b-form with 2-M reuse
        f4v accP[2][2];
        #pragma unroll
        for (int m = 0; m < 2; ++m) { accP[m][0] = zf; accP[m][1] = zf; }
        #pragma unroll 2
        for (int b = 0; b < 8; ++b) {
            float tb[2][4];
            #pragma unroll
            for (int m = 0; m < 2; ++m)
                #pragma unroll
                for (int rr = 0; rr < 4; ++rr)
                    tb[m][rr] = sBasT[b * 32 + m * 16 + 4 * kg + rr];
            #pragma unroll
            for (int nt = 0; nt < 2; ++nt) {
                s8v bv = *(const s8v*)(gBl3 + (size_t)b * 1280 + (16 * nt + r16) * 40 + 8 * kg);
                #pragma unroll
                for (int m = 0; m < 2; ++m) {
                    f4v D = __builtin_amdgcn_mfma_f32_16x16x32_bf16(avG2[m], bv, zf, 0, 0, 0);
                    #pragma unroll
                    for (int rr = 0; rr < 4; ++rr)
                        accP[m][nt][rr] += tb[m][rr] * D[rr];
                }
            }
        }
        // ii3 + combine + atomic p3n
        #pragma unroll
        for (int m = 0; m < 2; ++m) {
            #pragma unroll
            for (int nt = 0; nt < 2; ++nt)
                #pragma unroll
                for (int rr = 0; rr < 4; ++rr)
                    sT2[(4 * kg + rr) * 40 + 16 * nt + r16] = (u16)f2b(accP[m][nt][rr]);
            s8v av = *(const s8v*)(sT2 + r16 * 40 + 8 * kg);
            #pragma unroll
            for (int nt = 0; nt < 2; ++nt) {
                s8v bv = *(const s8v*)(gII3 + (16 * nt + r16) * 40 + 8 * kg);
                f4v ja = __builtin_amdgcn_mfma_f32_16x16x32_bf16(av, bv, zf, 0, 0, 0);
                #pragma unroll
                for (int rr = 0; rr < 4; ++rr) {
                    int rowD = m * 16 + 4 * kg + rr;
                    float i3a = tanhf_fast(ja[rr] + vii3[nt]);
                    float val = i3a * accT[m][2 + nt][rr] + sR3[d * 32 + rowD] * accT[m][4 + nt][rr];
                    atomicAdd(&p3n[((size_t)sIdxJ[rowD] * 3 + d) * 32 + 16 * nt + r16], val);
                }
            }
        }
    }
}

// ---------------- finalize: p1o = sum_d p3n^2 + p1n ; p3o = p3n * p1o -----
__global__ __launch_bounds__(256) void finalize_kernel(
    const float* __restrict__ p1n, const float* __restrict__ p3n,
    float* __restrict__ out)
{
    int t = blockIdx.x * 256 + threadIdx.x;
    int n = t >> 5, c = t & 31;
    float a0 = p3n[(n * 3 + 0) * 32 + c];
    float a1 = p3n[(n * 3 + 1) * 32 + c];
    float a2 = p3n[(n * 3 + 2) * 32 + c];
    float p1o = p1n[t] + a0 * a0 + a1 * a1 + a2 * a2;
    out[t] = p1o;
    float* o3 = out + NN * 32;
    o3[(n * 3 + 0) * 32 + c] = a0 * p1o;
    o3[(n * 3 + 1) * 32 + c] = a1 * p1o;
    o3[(n * 3 + 2) * 32 + c] = a2 * p1o;
}

extern "C" void kernel_launch(void* const* d_in, const int* in_sizes, int n_in,
                              void* d_out, int out_size, void* d_ws, size_t ws_size,
                              hipStream_t stream) {
    const float* p1     = (const float*)d_in[0];
    const float* p3     = (const float*)d_in[1];
    const float* r3     = (const float*)d_in[2];
    const float* basis  = (const float*)d_in[3];
    const int*   idx_i  = (const int*)d_in[4];
    const int*   idx_j  = (const int*)d_in[5];
    const float* pp1_W  = (const float*)d_in[6];
    const float* pp1_b  = (const float*)d_in[7];
    const float* pi1_W1 = (const float*)d_in[8];
    const float* pi1_b1 = (const float*)d_in[9];
    const float* pi1_W2 = (const float*)d_in[10];
    const float* pi1_b2 = (const float*)d_in[11];
    const float* pi1_W3 = (const float*)d_in[12];
    const float* ii1_W  = (const float*)d_in[13];
    const float* ii1_b  = (const float*)d_in[14];
    const float* pp3_W  = (const float*)d_in[15];
    const float* pp3_b  = (const float*)d_in[16];
    const float* pi3_W1 = (const float*)d_in[17];
    const float* pi3_b1 = (const float*)d_in[18];
    const float* pi3_W2 = (const float*)d_in[19];
    const float* pi3_b2 = (const float*)d_in[20];
    const float* pi3_W3 = (const float*)d_in[21];
    const float* ii3_W  = (const float*)d_in[22];
    const float* ii3_b  = (const float*)d_in[23];

    char* ws = (char*)d_ws;
    u16*   p1hb = (u16*)(ws + OFF_P1HB);
    u16*   p3hb = (u16*)(ws + OFF_P3HB);
    u16*   wb   = (u16*)(ws + OFF_WB);
    float* p1n  = (float*)(ws + OFF_P1N);
    float* p3n  = (float*)(ws + OFF_P3N);

    hipMemsetAsync(p1n, 0, 5120000, stream);

    node_prep<<<dim3(5000), dim3(256), 0, stream>>>(p1, p3, pp1_W, pp1_b, pp3_W, pp3_b, p1hb, p3hb);
    wprep<<<dim3((NWB + 255) / 256), dim3(256), 0, stream>>>(
        pi1_W1, pi1_W2, pi1_W3, ii1_W, pi3_W1, pi3_W2, pi3_W3, ii3_W, wb);

    edge_kernel<<<dim3(NE / 32), dim3(64), 0, stream>>>(
        p1hb, p3hb, r3, basis, idx_i, idx_j, wb,
        pi1_b1, pi1_b2, ii1_b, pi3_b1, pi3_b2, ii3_b,
        p1n, p3n);

    finalize_kernel<<<dim3(1250), dim3(256), 0, stream>>>(p1n, p3n, (float*)d_out);
}